// Round 3
// baseline (264.344 us; speedup 1.0000x reference)
//
#include <hip/hip_runtime.h>
#include <cstdint>
#include <cmath>

typedef uint32_t u32;
typedef unsigned short u16;
typedef float f32x4 __attribute__((ext_vector_type(4)));
typedef short bf16x8 __attribute__((ext_vector_type(8)));

#define NBATCH 8
#define CE 64
#define NPIX 16384

__device__ __forceinline__ u32 bf16_rne(float f) {
    u32 x = __float_as_uint(f);
    return (x + 0x7fffu + ((x >> 16) & 1u)) >> 16;
}

// ---------------------------------------------------------------------------
// K1: per-row LayerNorm over C=64 (stats written to HBM, xn NOT materialized),
// accumulate Gram partials G_b = xn^T xn (upper-triangle 8x8 tiles, fp32).
// grid 256 = 8 batches x 32 blocks, each block 512 rows (2 chunks of 256).
// ---------------------------------------------------------------------------
__global__ __launch_bounds__(256, 1) void k1_ln_gram(
    const float* __restrict__ x, const float* __restrict__ lnw, const float* __restrict__ lnb,
    float2* __restrict__ stats, float* __restrict__ gpart)
{
    __shared__ __align__(16) float sx[256][68];   // +4 pad: b128-aligned rows, bank spread
    __shared__ float gm[64][66];
    __shared__ float slw[64], slb[64];

    const int t = threadIdx.x;
    const int lane = t & 63;
    const int wv = t >> 6;
    const int blk = blockIdx.x;
    const int b = blk >> 5;
    const int n0 = (blk & 31) << 9;
    const float* xb = x + (size_t)b * (CE * NPIX);

    if (t < 64) { slw[t] = lnw[t]; slb[t] = lnb[t]; }

    const int ti = lane >> 3, tj = lane & 7;
    const bool ut = (ti <= tj);          // upper-triangle tiles only (G symmetric)
    const int i0 = ti << 3, j0 = tj << 3;
    float acc[8][8];
#pragma unroll
    for (int p = 0; p < 8; ++p)
#pragma unroll
        for (int q = 0; q < 8; ++q) acc[p][q] = 0.f;

    auto lnrow = [&](float* r, float& mu_o, float& rstd_o) {
        float s = 0.f;
#pragma unroll
        for (int cc = 0; cc < 64; ++cc) s += r[cc];
        float mu = s * 0.015625f;
        float v = 0.f;
#pragma unroll
        for (int cc = 0; cc < 64; ++cc) { float d = r[cc] - mu; v += d * d; }
        float rstd = rsqrtf(v * 0.015625f + 1e-5f);
#pragma unroll
        for (int cc = 0; cc < 64; ++cc) r[cc] = (r[cc] - mu) * rstd * slw[cc] + slb[cc];
        mu_o = mu; rstd_o = rstd;
    };
    auto stage = [&](const float* r) {
        // rotate write order by lane -> spread banks on ds_write
#pragma unroll
        for (int j = 0; j < 64; ++j) { int cc = (j + t) & 63; sx[t][cc] = r[cc]; }
    };
    auto gram = [&]() {
        if (ut) {
#pragma unroll 2
            for (int rr = 0; rr < 64; ++rr) {
                int r = (wv << 6) + rr;
                const float4 a0 = *(const float4*)&sx[r][i0];
                const float4 a1 = *(const float4*)&sx[r][i0 + 4];
                const float4 b0 = *(const float4*)&sx[r][j0];
                const float4 b1 = *(const float4*)&sx[r][j0 + 4];
                float av[8] = {a0.x, a0.y, a0.z, a0.w, a1.x, a1.y, a1.z, a1.w};
                float bv[8] = {b0.x, b0.y, b0.z, b0.w, b1.x, b1.y, b1.z, b1.w};
#pragma unroll
                for (int p = 0; p < 8; ++p)
#pragma unroll
                    for (int q = 0; q < 8; ++q) acc[p][q] = fmaf(av[p], bv[q], acc[p][q]);
            }
        }
    };

    float r0[64], r1[64];
#pragma unroll
    for (int cc = 0; cc < 64; ++cc) r0[cc] = xb[cc * NPIX + n0 + t];
    __syncthreads();                 // slw/slb visible
    float mu0, rs0;
    lnrow(r0, mu0, rs0);
    stats[(size_t)b * NPIX + n0 + t] = make_float2(mu0, rs0);
    stage(r0);
    // prefetch chunk 1 so HBM read overlaps Gram compute
#pragma unroll
    for (int cc = 0; cc < 64; ++cc) r1[cc] = xb[cc * NPIX + n0 + 256 + t];
    __syncthreads();
    gram();
    __syncthreads();
    float mu1, rs1;
    lnrow(r1, mu1, rs1);
    stats[(size_t)b * NPIX + n0 + 256 + t] = make_float2(mu1, rs1);
    stage(r1);
    __syncthreads();
    gram();
    __syncthreads();

    // merge 4 waves' partial tiles into gm (upper triangle only)
    for (int w = 0; w < 4; ++w) {
        if (wv == w && ut) {
#pragma unroll
            for (int p = 0; p < 8; ++p)
#pragma unroll
                for (int q = 0; q < 8; ++q) {
                    if (w == 0) gm[i0 + p][j0 + q] = acc[p][q];
                    else        gm[i0 + p][j0 + q] += acc[p][q];
                }
        }
        __syncthreads();
    }
    // write mirrored full 64x64 partial
#pragma unroll
    for (int i = 0; i < 16; ++i) {
        int e = t + (i << 8);
        int r = e >> 6, c2 = e & 63;
        float val = ((r >> 3) <= (c2 >> 3)) ? gm[r][c2] : gm[c2][r];
        gpart[(size_t)blk * 4096 + e] = val;
    }
}

// ---------------------------------------------------------------------------
// K2: per (b,h): reduce Gram partials -> G_b; attn_pre = wq_h^T G wk_h; *scale;
// softmax rows; fold into W2part = wv_h @ (attn^T wp_h). All fp32. grid 32.
// (The 32-partial reduce is redundant 4x per b, but gpart is 4 MB -> L2/L3 hits.)
// ---------------------------------------------------------------------------
__global__ __launch_bounds__(256) void k2_attn(
    const float* __restrict__ gpart, const float* __restrict__ wq, const float* __restrict__ wk,
    const float* __restrict__ wvm, const float* __restrict__ scale, const float* __restrict__ wp,
    float* __restrict__ w2part)
{
    __shared__ float sg[64][66], swk_[64][66], swq_[64][66], swv_[64][66], swp_[64][66];
    __shared__ float stmp[64][66], satt[64][66];
    const int t = threadIdx.x;
    const int b = blockIdx.x >> 2, h = blockIdx.x & 3;

#pragma unroll
    for (int i = 0; i < 16; ++i) {
        int e = t + (i << 8);
        int r = e >> 6, c = e & 63;
        float s = 0.f;
#pragma unroll 4
        for (int p = 0; p < 32; ++p) s += gpart[(size_t)(b * 32 + p) * 4096 + e];
        sg[r][c]   = s;
        swq_[r][c] = wq[r * 256 + h * 64 + c];
        swk_[r][c] = wk[r * 256 + h * 64 + c];
        swv_[r][c] = wvm[r * 256 + h * 64 + c];
        swp_[r][c] = wp[(h * 64 + r) * 64 + c];
    }
    __syncthreads();
    const int rr = t & 63, cb = (t >> 6) << 4;
    float a[16];

    // tmp[cc][e] = sum_k G[cc][k] * wk_h[k][e]
#pragma unroll
    for (int j = 0; j < 16; ++j) a[j] = 0.f;
    for (int k = 0; k < 64; ++k) {
        float g = sg[rr][k];
#pragma unroll
        for (int j = 0; j < 16; ++j) a[j] = fmaf(g, swk_[k][cb + j], a[j]);
    }
#pragma unroll
    for (int j = 0; j < 16; ++j) stmp[rr][cb + j] = a[j];
    __syncthreads();

    // attn_pre[d][e] = sum_cc wq_h[cc][d] * tmp[cc][e], times scale[h]
#pragma unroll
    for (int j = 0; j < 16; ++j) a[j] = 0.f;
    for (int k = 0; k < 64; ++k) {
        float qv = swq_[k][rr];
#pragma unroll
        for (int j = 0; j < 16; ++j) a[j] = fmaf(qv, stmp[k][cb + j], a[j]);
    }
    const float sc = scale[h];
#pragma unroll
    for (int j = 0; j < 16; ++j) satt[rr][cb + j] = a[j] * sc;
    __syncthreads();

    // softmax over e (row-wise), wave 0
    if (t < 64) {
        float m = -3.4e38f;
        for (int e = 0; e < 64; ++e) m = fmaxf(m, satt[t][e]);
        float s = 0.f;
        for (int e = 0; e < 64; ++e) { float p = expf(satt[t][e] - m); satt[t][e] = p; s += p; }
        float inv = 1.0f / s;
        for (int e = 0; e < 64; ++e) satt[t][e] *= inv;
    }
    __syncthreads();

    // weff[e][c] = sum_d attn[d][e] * wp_h[d][c]   -> stmp
#pragma unroll
    for (int j = 0; j < 16; ++j) a[j] = 0.f;
    for (int k = 0; k < 64; ++k) {
        float av = satt[k][rr];
#pragma unroll
        for (int j = 0; j < 16; ++j) a[j] = fmaf(av, swp_[k][cb + j], a[j]);
    }
    __syncthreads();
#pragma unroll
    for (int j = 0; j < 16; ++j) stmp[rr][cb + j] = a[j];
    __syncthreads();

    // w2p[ci][c] = sum_e wv_h[ci][e] * weff[e][c]  -> satt (reused as staging)
#pragma unroll
    for (int j = 0; j < 16; ++j) a[j] = 0.f;
    for (int k = 0; k < 64; ++k) {
        float vv = swv_[rr][k];
#pragma unroll
        for (int j = 0; j < 16; ++j) a[j] = fmaf(vv, stmp[k][cb + j], a[j]);
    }
    __syncthreads();
#pragma unroll
    for (int j = 0; j < 16; ++j) satt[rr][cb + j] = a[j];
    __syncthreads();
#pragma unroll
    for (int i = 0; i < 16; ++i) {
        int e = t + (i << 8);
        w2part[(size_t)blockIdx.x * 4096 + e] = satt[e >> 6][e & 63];
    }
}

// ---------------------------------------------------------------------------
// K2b: W2[b] = sum_h W2part, transpose + split-bf16 pack -> w2t[b][c'][cc(pad72)]
// grid 32 = 8 batches x 4 segs
// ---------------------------------------------------------------------------
__global__ __launch_bounds__(256) void k2b_pack(
    const float* __restrict__ w2part, u16* __restrict__ th, u16* __restrict__ tl)
{
    int b = blockIdx.x >> 2, seg = blockIdx.x & 3, t = threadIdx.x;
#pragma unroll
    for (int i = 0; i < 4; ++i) {
        int e = (seg << 10) + t + (i << 8);   // e = cc*64 + c'
        int cc = e >> 6, cp = e & 63;
        float s = 0.f;
#pragma unroll
        for (int h = 0; h < 4; ++h) s += w2part[(size_t)(b * 4 + h) * 4096 + e];
        u32 hb = bf16_rne(s);
        u32 lb = bf16_rne(s - __uint_as_float(hb << 16));
        th[b * 4608 + cp * 72 + cc] = (u16)hb;
        tl[b * 4608 + cp * 72 + cc] = (u16)lb;
    }
}

// ---------------------------------------------------------------------------
// K3: reconstruct xn rows from x + (mu,rstd) stats (split-bf16, XOR-swizzled,
// in-LDS), fused proj (3-pass split-bf16 MFMA) + depthwise conv1 + exact GELU
// + depthwise conv2. grid 2048 = (b, c, strip s of 32 h-rows). 256 thr.
// The proj flat (n,c') buffer IS the conv (h,w) plane for channel c:
//   conv pixel (h,w) = proj row n = c*256 + 2h + (w>>6), col c' = w&63.
// ---------------------------------------------------------------------------
__global__ __launch_bounds__(256, 2) void k3_proj_conv(
    const float* __restrict__ x, const float2* __restrict__ stats,
    const float* __restrict__ lnw, const float* __restrict__ lnb,
    const u16* __restrict__ w2th, const u16* __restrict__ w2tl,
    const float* __restrict__ bp, const float* __restrict__ c1w, const float* __restrict__ c2w,
    float* __restrict__ out)
{
    __shared__ __align__(16) u16 sah[80 * 64];
    __shared__ __align__(16) u16 sal[80 * 64];
    __shared__ __align__(16) u16 swh[64 * 72];
    __shared__ __align__(16) u16 swl[64 * 72];
    __shared__ float plane[72 * 64];
    __shared__ float c1b[34 * 128];

    const int t = threadIdx.x;
    const int lane = t & 63;
    const int wvi = t >> 6;
    const int bid = blockIdx.x;
    const int s4 = bid & 3;
    const int c = (bid >> 2) & 63;
    const int b = bid >> 8;
    const int h0 = s4 << 5;
    const int rs = max(0, 2 * h0 - 4);
    const int re = min(256, 2 * h0 + 68);
    const int R = re - rs;                       // 68 or 72 proj rows staged

    // ---- stage: x -> xn (affine per row) -> split-bf16 into sah/sal ----
    {
        const float* xb = x + (size_t)b * (CE * NPIX);
        const float2* st = stats + ((size_t)b * NPIX + c * 256 + rs);
        const int nn0 = c * 256 + rs;
        for (int j = 0; j < 8; ++j) {
            int i = (j << 8) + t;                // 0..2047
            int row = i & 127;
            int ccq = i >> 7;                    // 0..15
            if (row < R) {
                int cc0 = ccq << 2;
                float2 ms = st[row];
                float4 lw  = *(const float4*)(lnw + cc0);
                float4 lb4 = *(const float4*)(lnb + cc0);
                size_t gidx = (size_t)cc0 * NPIX + nn0 + row;
                float v0 = xb[gidx];
                float v1 = xb[gidx + NPIX];
                float v2 = xb[gidx + 2 * NPIX];
                float v3 = xb[gidx + 3 * NPIX];
                float x0 = fmaf((v0 - ms.x) * ms.y, lw.x, lb4.x);
                float x1 = fmaf((v1 - ms.x) * ms.y, lw.y, lb4.y);
                float x2 = fmaf((v2 - ms.x) * ms.y, lw.z, lb4.z);
                float x3 = fmaf((v3 - ms.x) * ms.y, lw.w, lb4.w);
                ushort4 hv, lv;
                u32 hb;
                hb = bf16_rne(x0); hv.x = (u16)hb; lv.x = (u16)bf16_rne(x0 - __uint_as_float(hb << 16));
                hb = bf16_rne(x1); hv.y = (u16)hb; lv.y = (u16)bf16_rne(x1 - __uint_as_float(hb << 16));
                hb = bf16_rne(x2); hv.z = (u16)hb; lv.z = (u16)bf16_rne(x2 - __uint_as_float(hb << 16));
                hb = bf16_rne(x3); hv.w = (u16)hb; lv.w = (u16)bf16_rne(x3 - __uint_as_float(hb << 16));
                int cs = cc0 ^ (((rs + row) & 7) << 3);   // XOR-swizzle (elem bits 3-5)
                int base = (row << 6) + cs;
                *(ushort4*)(sah + base) = hv;
                *(ushort4*)(sal + base) = lv;
            }
        }
        const uint4* wsrcH = (const uint4*)(w2th + (size_t)b * 4608);
        const uint4* wsrcL = (const uint4*)(w2tl + (size_t)b * 4608);
        for (int i = t; i < 576; i += 256) {
            ((uint4*)swh)[i] = wsrcH[i];
            ((uint4*)swl)[i] = wsrcL[i];
        }
    }
    __syncthreads();

    // ---- proj GEMM: D[row][col] = sum_cc xn[row][cc] * W2[cc][col] ----
    const int col = (wvi << 4) + (lane & 15);    // wave w owns cols [16w,16w+16)
    const int kg = lane >> 4;
    f32x4 pacc[5];
#pragma unroll
    for (int mt = 0; mt < 5; ++mt) pacc[mt] = (f32x4){0.f, 0.f, 0.f, 0.f};
#pragma unroll
    for (int kk = 0; kk < 2; ++kk) {
        const int k0 = (kk << 5) + (kg << 3);
        bf16x8 bh = *(const bf16x8*)&swh[col * 72 + k0];
        bf16x8 bl = *(const bf16x8*)&swl[col * 72 + k0];
        bf16x8 ah[5], al[5];
#pragma unroll
        for (int mt = 0; mt < 5; ++mt) {
            int row = (mt << 4) + (lane & 15);
            int sz = (rs + row) & 7;
            int idx = (row << 6) + (k0 ^ (sz << 3));   // undo stage's XOR swizzle
            ah[mt] = *(const bf16x8*)&sah[idx];
            al[mt] = *(const bf16x8*)&sal[idx];
        }
#pragma unroll
        for (int mt = 0; mt < 5; ++mt)
            pacc[mt] = __builtin_amdgcn_mfma_f32_16x16x32_bf16(ah[mt], bh, pacc[mt], 0, 0, 0);
#pragma unroll
        for (int mt = 0; mt < 5; ++mt)
            pacc[mt] = __builtin_amdgcn_mfma_f32_16x16x32_bf16(ah[mt], bl, pacc[mt], 0, 0, 0);
#pragma unroll
        for (int mt = 0; mt < 5; ++mt)
            pacc[mt] = __builtin_amdgcn_mfma_f32_16x16x32_bf16(al[mt], bh, pacc[mt], 0, 0, 0);
    }
    const float bpv = bp[col];
#pragma unroll
    for (int mt = 0; mt < 5; ++mt) {
#pragma unroll
        for (int r = 0; r < 4; ++r) {
            int row = (mt << 4) + (kg << 2) + r;       // D row = (lane>>4)*4 + reg
            if (row < R) plane[(row << 6) + col] = pacc[mt][r] + bpv;
        }
    }
    __syncthreads();

    // ---- conv1 (3x3 depthwise, zero pad) + exact GELU ----
    float wA[9], wB[9];
#pragma unroll
    for (int q = 0; q < 9; ++q) { wA[q] = c1w[c * 9 + q]; wB[q] = c2w[c * 9 + q]; }
    const int wcol = t & 127;
    const int half = t >> 7;
    const int h1s = max(h0 - 1, 0), h1e = min(h0 + 33, 128);
    const int C1 = h1e - h1s;
    const int pbias = rs << 6;                   // plane idx = h*128 + w - rs*64
    {
        auto rd3 = [&](int hh, float& u0, float& u1, float& u2) {
            if (hh >= 0 && hh < 128) {
                int base = hh * 128 - pbias + wcol;
                u0 = (wcol > 0)   ? plane[base - 1] : 0.f;
                u1 = plane[base];
                u2 = (wcol < 127) ? plane[base + 1] : 0.f;
            } else { u0 = u1 = u2 = 0.f; }
        };
        int rA = (half == 0) ? 0 : ((C1 + 1) >> 1);
        int rB = (half == 0) ? ((C1 + 1) >> 1) : C1;
        float m0, m1, m2, n0_, n1_, n2_, p0, p1, p2;
        int h1 = h1s + rA;
        rd3(h1 - 1, m0, m1, m2);
        rd3(h1, n0_, n1_, n2_);
        for (int r = rA; r < rB; ++r, ++h1) {
            rd3(h1 + 1, p0, p1, p2);
            float sum = m0 * wA[0] + m1 * wA[1] + m2 * wA[2]
                      + n0_ * wA[3] + n1_ * wA[4] + n2_ * wA[5]
                      + p0 * wA[6] + p1 * wA[7] + p2 * wA[8];
            float g = 0.5f * sum * (1.f + erff(sum * 0.70710678118654752f));
            c1b[r * 128 + wcol] = g;
            m0 = n0_; m1 = n1_; m2 = n2_;
            n0_ = p0; n1_ = p1; n2_ = p2;
        }
    }
    __syncthreads();

    // ---- conv2 + global store ----
    {
        auto rd3b = [&](int hh, float& u0, float& u1, float& u2) {
            if (hh >= h1s && hh < h1e) {         // staged range == valid rows; else global zero pad
                int base = (hh - h1s) * 128 + wcol;
                u0 = (wcol > 0)   ? c1b[base - 1] : 0.f;
                u1 = c1b[base];
                u2 = (wcol < 127) ? c1b[base + 1] : 0.f;
            } else { u0 = u1 = u2 = 0.f; }
        };
        float q0, q1, q2, r0f, r1f, r2f, s0, s1, s2;
        int h2 = h0 + (half << 4);
        rd3b(h2 - 1, q0, q1, q2);
        rd3b(h2, r0f, r1f, r2f);
        float* ob = out + ((size_t)b * 64 + c) * 16384;
        for (int r = 0; r < 16; ++r, ++h2) {
            rd3b(h2 + 1, s0, s1, s2);
            float sum = q0 * wB[0] + q1 * wB[1] + q2 * wB[2]
                      + r0f * wB[3] + r1f * wB[4] + r2f * wB[5]
                      + s0 * wB[6] + s1 * wB[7] + s2 * wB[8];
            ob[h2 * 128 + wcol] = sum;
            q0 = r0f; q1 = r1f; q2 = r2f;
            r0f = s0; r1f = s1; r2f = s2;
        }
    }
}

// ---------------------------------------------------------------------------
extern "C" void kernel_launch(void* const* d_in, const int* in_sizes, int n_in,
                              void* d_out, int out_size, void* d_ws, size_t ws_size,
                              hipStream_t stream)
{
    const float* x   = (const float*)d_in[0];
    const float* lnw = (const float*)d_in[1];
    const float* lnb = (const float*)d_in[2];
    const float* wq  = (const float*)d_in[3];
    const float* wk  = (const float*)d_in[4];
    const float* wv  = (const float*)d_in[5];
    const float* sc  = (const float*)d_in[6];
    const float* wp  = (const float*)d_in[7];
    const float* bp  = (const float*)d_in[8];
    const float* c1w = (const float*)d_in[9];
    const float* c2w = (const float*)d_in[10];
    float* out = (float*)d_out;

    char* ws = (char*)d_ws;
    float*  gpart = (float*)(ws);                 // 4,194,304 B (256 x 4096 f32)
    float2* stats = (float2*)(ws + 4194304);      // 1,048,576 B (131072 float2)
    float*  w2p   = (float*)(ws + 5242880);       //   524,288 B
    u16*    w2th  = (u16*)(ws + 5767168);         //    73,728 B
    u16*    w2tl  = (u16*)(ws + 5840896);         //    73,728 B  (total 5,914,624 B)

    hipLaunchKernelGGL(k1_ln_gram, dim3(256), dim3(256), 0, stream, x, lnw, lnb, stats, gpart);
    hipLaunchKernelGGL(k2_attn, dim3(32), dim3(256), 0, stream, gpart, wq, wk, wv, sc, wp, w2p);
    hipLaunchKernelGGL(k2b_pack, dim3(32), dim3(256), 0, stream, w2p, w2th, w2tl);
    hipLaunchKernelGGL(k3_proj_conv, dim3(2048), dim3(256), 0, stream,
                       x, stats, lnw, lnb, w2th, w2tl, bp, c1w, c2w, out);
}

// Round 6
// 200.122 us; speedup vs baseline: 1.3209x; 1.3209x over previous
//
#include <hip/hip_runtime.h>
#include <cstdint>
#include <cmath>

typedef uint32_t u32;
typedef unsigned short u16;
typedef float f32x4 __attribute__((ext_vector_type(4)));
typedef short bf16x8 __attribute__((ext_vector_type(8)));

#define NBATCH 8
#define CE 64
#define NPIX 16384

__device__ __forceinline__ u32 bf16_rne(float f) {
    u32 x = __float_as_uint(f);
    return (x + 0x7fffu + ((x >> 16) & 1u)) >> 16;
}

// ---------------------------------------------------------------------------
// K1: per-row LayerNorm over C=64 (stats -> HBM, xn NOT materialized),
// Gram partials G_b = xn^T xn (upper-triangle 8x8 tiles, fp32).
// grid 512 = 8 batches x 64 segs, each block ONE chunk of 256 rows ->
// 2 blocks/CU co-resident (LDS 70 KB each): phases overlap across blocks.
// ---------------------------------------------------------------------------
__global__ __launch_bounds__(256, 2) void k1_ln_gram(
    const float* __restrict__ x, const float* __restrict__ lnw, const float* __restrict__ lnb,
    float2* __restrict__ stats, float* __restrict__ gpart)
{
    __shared__ __align__(16) float sx[256][68];   // 69632 B; +4 pad: 16B-aligned rows
    __shared__ float slw[64], slb[64];

    const int t = threadIdx.x;
    const int lane = t & 63;
    const int wv = t >> 6;
    const int blk = blockIdx.x;
    const int b = blk >> 6;
    const int n0 = (blk & 63) << 8;
    const float* xb = x + (size_t)b * (CE * NPIX);

    if (t < 64) { slw[t] = lnw[t]; slb[t] = lnb[t]; }

    const int ti = lane >> 3, tj = lane & 7;
    const bool ut = (ti <= tj);          // upper-triangle tiles only (G symmetric)
    const int i0 = ti << 3, j0 = tj << 3;
    float acc[8][8];
#pragma unroll
    for (int p = 0; p < 8; ++p)
#pragma unroll
        for (int q = 0; q < 8; ++q) acc[p][q] = 0.f;

    // load one 256-row chunk (coalesced 256B segments per channel)
    float r0[64];
#pragma unroll
    for (int cc = 0; cc < 64; ++cc) r0[cc] = xb[cc * NPIX + n0 + t];
    __syncthreads();                 // slw/slb visible

    // LayerNorm row t
    {
        float s = 0.f;
#pragma unroll
        for (int cc = 0; cc < 64; ++cc) s += r0[cc];
        float mu = s * 0.015625f;
        float v = 0.f;
#pragma unroll
        for (int cc = 0; cc < 64; ++cc) { float d = r0[cc] - mu; v += d * d; }
        float rstd = rsqrtf(v * 0.015625f + 1e-5f);
#pragma unroll
        for (int cc = 0; cc < 64; ++cc) r0[cc] = (r0[cc] - mu) * rstd * slw[cc] + slb[cc];
        stats[(size_t)b * NPIX + n0 + t] = make_float2(mu, rstd);
    }
    // stage: rotate write order by lane -> bank = (5t+j) mod 32, 2-way (free)
#pragma unroll
    for (int j = 0; j < 64; ++j) { int cc = (j + t) & 63; sx[t][cc] = r0[cc]; }
    __syncthreads();

    // Gram over this block's 256 rows (wave wv covers rows wv*64..wv*64+63)
    if (ut) {
#pragma unroll 2
        for (int rr = 0; rr < 64; ++rr) {
            int r = (wv << 6) + rr;
            const float4 a0 = *(const float4*)&sx[r][i0];
            const float4 a1 = *(const float4*)&sx[r][i0 + 4];
            const float4 b0 = *(const float4*)&sx[r][j0];
            const float4 b1 = *(const float4*)&sx[r][j0 + 4];
            float av[8] = {a0.x, a0.y, a0.z, a0.w, a1.x, a1.y, a1.z, a1.w};
            float bv[8] = {b0.x, b0.y, b0.z, b0.w, b1.x, b1.y, b1.z, b1.w};
#pragma unroll
            for (int p = 0; p < 8; ++p)
#pragma unroll
                for (int q = 0; q < 8; ++q) acc[p][q] = fmaf(av[p], bv[q], acc[p][q]);
        }
    }
    __syncthreads();                 // sx reads done -> safe to alias gm over sx

    float (*gm)[66] = (float (*)[66])&sx[0][0];   // 64x66 floats, fits in sx
    for (int w = 0; w < 4; ++w) {
        if (wv == w && ut) {
#pragma unroll
            for (int p = 0; p < 8; ++p)
#pragma unroll
                for (int q = 0; q < 8; ++q) {
                    if (w == 0) gm[i0 + p][j0 + q] = acc[p][q];
                    else        gm[i0 + p][j0 + q] += acc[p][q];
                }
        }
        __syncthreads();
    }
    // write mirrored full 64x64 partial
#pragma unroll
    for (int i = 0; i < 16; ++i) {
        int e = t + (i << 8);
        int r = e >> 6, c2 = e & 63;
        float val = ((r >> 3) <= (c2 >> 3)) ? gm[r][c2] : gm[c2][r];
        gpart[(size_t)blk * 4096 + e] = val;
    }
}

// ---------------------------------------------------------------------------
// K1b: wide reduce of 64 Gram partials per batch. grid 128 = 8 b x 16 segs.
// 512 waves; 8 MB read at HBM/L2 rate with 4 ILP chains.
// ---------------------------------------------------------------------------
__global__ __launch_bounds__(256) void k1b_reduce(
    const float* __restrict__ gpart, float* __restrict__ G)
{
    int b = blockIdx.x >> 4;
    int e = ((blockIdx.x & 15) << 8) + threadIdx.x;
    float s0 = 0.f, s1 = 0.f, s2 = 0.f, s3 = 0.f;
#pragma unroll
    for (int p = 0; p < 64; p += 4) {
        s0 += gpart[(size_t)(b * 64 + p) * 4096 + e];
        s1 += gpart[(size_t)(b * 64 + p + 1) * 4096 + e];
        s2 += gpart[(size_t)(b * 64 + p + 2) * 4096 + e];
        s3 += gpart[(size_t)(b * 64 + p + 3) * 4096 + e];
    }
    G[b * 4096 + e] = (s0 + s1) + (s2 + s3);
}

// ---------------------------------------------------------------------------
// K2: per (b,h): attn_pre = wq_h^T G wk_h; *scale; softmax rows (parallel);
// fold into W2part = wv_h @ (attn^T wp_h). All fp32. grid 32.
// ---------------------------------------------------------------------------
__global__ __launch_bounds__(256) void k2_attn(
    const float* __restrict__ G, const float* __restrict__ wq, const float* __restrict__ wk,
    const float* __restrict__ wvm, const float* __restrict__ scale, const float* __restrict__ wp,
    float* __restrict__ w2part)
{
    __shared__ float sg[64][66], swk_[64][66], swq_[64][66], swv_[64][66], swp_[64][66];
    __shared__ float stmp[64][66], satt[64][66];
    const int t = threadIdx.x;
    const int b = blockIdx.x >> 2, h = blockIdx.x & 3;

#pragma unroll
    for (int i = 0; i < 16; ++i) {
        int e = t + (i << 8);
        int r = e >> 6, c = e & 63;
        sg[r][c]   = G[b * 4096 + e];
        swq_[r][c] = wq[r * 256 + h * 64 + c];
        swk_[r][c] = wk[r * 256 + h * 64 + c];
        swv_[r][c] = wvm[r * 256 + h * 64 + c];
        swp_[r][c] = wp[(h * 64 + r) * 64 + c];
    }
    __syncthreads();
    const int rr = t & 63, cb = (t >> 6) << 4;
    float a[16];

    // tmp[cc][e] = sum_k G[cc][k] * wk_h[k][e]
#pragma unroll
    for (int j = 0; j < 16; ++j) a[j] = 0.f;
    for (int k = 0; k < 64; ++k) {
        float g = sg[rr][k];
#pragma unroll
        for (int j = 0; j < 16; ++j) a[j] = fmaf(g, swk_[k][cb + j], a[j]);
    }
#pragma unroll
    for (int j = 0; j < 16; ++j) stmp[rr][cb + j] = a[j];
    __syncthreads();

    // attn_pre[d][e] = sum_cc wq_h[cc][d] * tmp[cc][e], times scale[h]
#pragma unroll
    for (int j = 0; j < 16; ++j) a[j] = 0.f;
    for (int k = 0; k < 64; ++k) {
        float qv = swq_[k][rr];
#pragma unroll
        for (int j = 0; j < 16; ++j) a[j] = fmaf(qv, stmp[k][cb + j], a[j]);
    }
    const float sc = scale[h];
#pragma unroll
    for (int j = 0; j < 16; ++j) satt[rr][cb + j] = a[j] * sc;
    __syncthreads();

    // parallel softmax over e: 4 threads per row, 16 cols each
    {
        const int row = t & 63, q = t >> 6, c0 = q << 4;
        float m = -3.4e38f;
#pragma unroll
        for (int j = 0; j < 16; ++j) m = fmaxf(m, satt[row][c0 + j]);
        stmp[row][q] = m;
        __syncthreads();
        m = fmaxf(fmaxf(stmp[row][0], stmp[row][1]), fmaxf(stmp[row][2], stmp[row][3]));
        float s = 0.f;
#pragma unroll
        for (int j = 0; j < 16; ++j) {
            float p = expf(satt[row][c0 + j] - m);
            satt[row][c0 + j] = p; s += p;
        }
        stmp[row][4 + q] = s;
        __syncthreads();
        float inv = 1.0f / ((stmp[row][4] + stmp[row][5]) + (stmp[row][6] + stmp[row][7]));
#pragma unroll
        for (int j = 0; j < 16; ++j) satt[row][c0 + j] *= inv;
    }
    __syncthreads();

    // weff[e][c] = sum_d attn[d][e] * wp_h[d][c]   -> stmp
#pragma unroll
    for (int j = 0; j < 16; ++j) a[j] = 0.f;
    for (int k = 0; k < 64; ++k) {
        float av = satt[k][rr];
#pragma unroll
        for (int j = 0; j < 16; ++j) a[j] = fmaf(av, swp_[k][cb + j], a[j]);
    }
    __syncthreads();
#pragma unroll
    for (int j = 0; j < 16; ++j) stmp[rr][cb + j] = a[j];
    __syncthreads();

    // w2p[ci][c] = sum_e wv_h[ci][e] * weff[e][c]  -> satt (reused)
#pragma unroll
    for (int j = 0; j < 16; ++j) a[j] = 0.f;
    for (int k = 0; k < 64; ++k) {
        float vv = swv_[rr][k];
#pragma unroll
        for (int j = 0; j < 16; ++j) a[j] = fmaf(vv, stmp[k][cb + j], a[j]);
    }
    __syncthreads();
#pragma unroll
    for (int j = 0; j < 16; ++j) satt[rr][cb + j] = a[j];
    __syncthreads();
#pragma unroll
    for (int i = 0; i < 16; ++i) {
        int e = t + (i << 8);
        w2part[(size_t)blockIdx.x * 4096 + e] = satt[e >> 6][e & 63];
    }
}

// ---------------------------------------------------------------------------
// K2b: W2[b] = sum_h W2part, transpose + split-bf16 pack -> w2t[b][c'][cc(pad72)]
// Output-major: grid 8 (batch) x 512 thr, 9 coalesced outputs each
// (4608 = 9*512). Gather reads are L2-hot (w2p = 512 KB).
// ---------------------------------------------------------------------------
__global__ __launch_bounds__(512) void k2b_pack(
    const float* __restrict__ w2part, u16* __restrict__ th, u16* __restrict__ tl)
{
    const int b = blockIdx.x, t = threadIdx.x;
    const float* wp0 = w2part + (size_t)b * 4 * 4096;
#pragma unroll
    for (int i = 0; i < 9; ++i) {
        int o = i * 512 + t;                  // o = cp*72 + cc
        int cp = o / 72, cc = o - cp * 72;
        u32 hb = 0, lb = 0;
        if (cc < 64) {
            int e = cc * 64 + cp;
            float s = ((wp0[e] + wp0[4096 + e]) + (wp0[8192 + e] + wp0[12288 + e]));
            hb = bf16_rne(s);
            lb = bf16_rne(s - __uint_as_float(hb << 16));
        }
        th[b * 4608 + o] = (u16)hb;
        tl[b * 4608 + o] = (u16)lb;
    }
}

// ---------------------------------------------------------------------------
// K3: reconstruct xn rows from x + stats (split-bf16, XOR-swizzled, in-LDS),
// fused proj (3-pass split-bf16 MFMA) + dw-conv1 + exact GELU + dw-conv2.
// grid 2048 = (b, c, strip of 32 h-rows). LDS phase-aliased to 36.9 KB ->
// 3 blocks/CU. plane aliases sah/sal; c1b aliases swh/swl (sync-protected).
// conv pixel (h,w) = proj row n = c*256 + 2h + (w>>6), col c' = w&63.
// ---------------------------------------------------------------------------
__global__ __launch_bounds__(256, 3) void k3_proj_conv(
    const float* __restrict__ x, const float2* __restrict__ stats,
    const float* __restrict__ lnw, const float* __restrict__ lnb,
    const u16* __restrict__ w2th, const u16* __restrict__ w2tl,
    const float* __restrict__ bp, const float* __restrict__ c1w, const float* __restrict__ c2w,
    float* __restrict__ out)
{
    __shared__ __align__(16) char smem[36864];
    u16* sah = (u16*)smem;                  // [72*64] u16, 9216 B
    u16* sal = (u16*)(smem + 9216);         // [72*64]
    u16* swh = (u16*)(smem + 18432);        // [64*72]
    u16* swl = (u16*)(smem + 27648);        // [64*72]
    float* plane = (float*)smem;            // [72*64] f32 — aliases sah/sal
    float* c1b   = (float*)(smem + 18432);  // [34*128] f32 — aliases swh/swl

    const int t = threadIdx.x;
    const int lane = t & 63;
    const int wvi = t >> 6;
    const int bid = blockIdx.x;
    const int s4 = bid & 3;
    const int c = (bid >> 2) & 63;
    const int b = bid >> 8;
    const int h0 = s4 << 5;
    const int rs = max(0, 2 * h0 - 4);
    const int re = min(256, 2 * h0 + 68);
    const int R = re - rs;                       // 68 or 72 proj rows staged

    const float bpv = bp[(wvi << 4) + (lane & 15)];   // early: hide latency

    // ---- stage: x -> xn (affine) -> split-bf16 into sah/sal; W2T -> swh/swl
    {
        const float* xb = x + (size_t)b * (CE * NPIX);
        const float2* st = stats + ((size_t)b * NPIX + c * 256 + rs);
        const int nn0 = c * 256 + rs;
#pragma unroll
        for (int j = 0; j < 8; ++j) {
            int i = (j << 8) + t;                // 0..2047
            int row = i & 127;
            int ccq = i >> 7;                    // 0..15
            if (row < R) {
                int cc0 = ccq << 2;
                float2 ms = st[row];
                float4 lw  = *(const float4*)(lnw + cc0);
                float4 lb4 = *(const float4*)(lnb + cc0);
                size_t gidx = (size_t)cc0 * NPIX + nn0 + row;
                float v0 = xb[gidx];
                float v1 = xb[gidx + NPIX];
                float v2 = xb[gidx + 2 * NPIX];
                float v3 = xb[gidx + 3 * NPIX];
                float x0 = fmaf((v0 - ms.x) * ms.y, lw.x, lb4.x);
                float x1 = fmaf((v1 - ms.x) * ms.y, lw.y, lb4.y);
                float x2 = fmaf((v2 - ms.x) * ms.y, lw.z, lb4.z);
                float x3 = fmaf((v3 - ms.x) * ms.y, lw.w, lb4.w);
                ushort4 hv, lv;
                u32 hb;
                hb = bf16_rne(x0); hv.x = (u16)hb; lv.x = (u16)bf16_rne(x0 - __uint_as_float(hb << 16));
                hb = bf16_rne(x1); hv.y = (u16)hb; lv.y = (u16)bf16_rne(x1 - __uint_as_float(hb << 16));
                hb = bf16_rne(x2); hv.z = (u16)hb; lv.z = (u16)bf16_rne(x2 - __uint_as_float(hb << 16));
                hb = bf16_rne(x3); hv.w = (u16)hb; lv.w = (u16)bf16_rne(x3 - __uint_as_float(hb << 16));
                int cs = cc0 ^ (((rs + row) & 7) << 3);   // XOR-swizzle (elem bits 3-5)
                int base = (row << 6) + cs;
                *(ushort4*)(sah + base) = hv;
                *(ushort4*)(sal + base) = lv;
            }
        }
        const uint4* wsrcH = (const uint4*)(w2th + (size_t)b * 4608);
        const uint4* wsrcL = (const uint4*)(w2tl + (size_t)b * 4608);
        for (int i = t; i < 576; i += 256) {
            ((uint4*)swh)[i] = wsrcH[i];
            ((uint4*)swl)[i] = wsrcL[i];
        }
    }
    __syncthreads();

    // ---- proj GEMM: D[row][col] = sum_cc xn[row][cc] * W2[cc][col] ----
    const int col = (wvi << 4) + (lane & 15);    // wave w owns cols [16w,16w+16)
    const int kg = lane >> 4;
    f32x4 pacc[5];
#pragma unroll
    for (int mt = 0; mt < 5; ++mt) pacc[mt] = (f32x4){0.f, 0.f, 0.f, 0.f};
#pragma unroll
    for (int kk = 0; kk < 2; ++kk) {
        const int k0 = (kk << 5) + (kg << 3);
        bf16x8 bh = *(const bf16x8*)&swh[col * 72 + k0];
        bf16x8 bl = *(const bf16x8*)&swl[col * 72 + k0];
#pragma unroll
        for (int mt = 0; mt < 5; ++mt) {
            int row = (mt << 4) + (lane & 15);
            int sz = (rs + row) & 7;
            int idx = (row << 6) + (k0 ^ (sz << 3));   // undo stage's XOR swizzle
            bf16x8 ah = *(const bf16x8*)&sah[idx];
            bf16x8 al = *(const bf16x8*)&sal[idx];
            pacc[mt] = __builtin_amdgcn_mfma_f32_16x16x32_bf16(ah, bh, pacc[mt], 0, 0, 0);
            pacc[mt] = __builtin_amdgcn_mfma_f32_16x16x32_bf16(ah, bl, pacc[mt], 0, 0, 0);
            pacc[mt] = __builtin_amdgcn_mfma_f32_16x16x32_bf16(al, bh, pacc[mt], 0, 0, 0);
        }
    }
    __syncthreads();     // all LDS reads of sah/sal/swh/swl done -> alias safe

    // ---- write plane (aliases sah/sal) ----
#pragma unroll
    for (int mt = 0; mt < 5; ++mt) {
#pragma unroll
        for (int r = 0; r < 4; ++r) {
            int row = (mt << 4) + (kg << 2) + r;       // D row = (lane>>4)*4 + reg
            if (row < R) plane[(row << 6) + col] = pacc[mt][r] + bpv;
        }
    }
    __syncthreads();

    // ---- conv1 (3x3 depthwise, zero pad) + exact GELU -> c1b (aliases swh/swl)
    float wA[9], wB[9];
#pragma unroll
    for (int q = 0; q < 9; ++q) { wA[q] = c1w[c * 9 + q]; wB[q] = c2w[c * 9 + q]; }
    const int wcol = t & 127;
    const int half = t >> 7;
    const int h1s = max(h0 - 1, 0), h1e = min(h0 + 33, 128);
    const int C1 = h1e - h1s;
    const int pbias = rs << 6;                   // plane idx = h*128 + w - rs*64
    {
        auto rd3 = [&](int hh, float& u0, float& u1, float& u2) {
            if (hh >= 0 && hh < 128) {
                int base = hh * 128 - pbias + wcol;
                u0 = (wcol > 0)   ? plane[base - 1] : 0.f;
                u1 = plane[base];
                u2 = (wcol < 127) ? plane[base + 1] : 0.f;
            } else { u0 = u1 = u2 = 0.f; }
        };
        int rA = (half == 0) ? 0 : ((C1 + 1) >> 1);
        int rB = (half == 0) ? ((C1 + 1) >> 1) : C1;
        float m0, m1, m2, n0_, n1_, n2_, p0, p1, p2;
        int h1 = h1s + rA;
        rd3(h1 - 1, m0, m1, m2);
        rd3(h1, n0_, n1_, n2_);
        for (int r = rA; r < rB; ++r, ++h1) {
            rd3(h1 + 1, p0, p1, p2);
            float sum = m0 * wA[0] + m1 * wA[1] + m2 * wA[2]
                      + n0_ * wA[3] + n1_ * wA[4] + n2_ * wA[5]
                      + p0 * wA[6] + p1 * wA[7] + p2 * wA[8];
            float g = 0.5f * sum * (1.f + erff(sum * 0.70710678118654752f));
            c1b[r * 128 + wcol] = g;
            m0 = n0_; m1 = n1_; m2 = n2_;
            n0_ = p0; n1_ = p1; n2_ = p2;
        }
    }
    __syncthreads();

    // ---- conv2 + global store ----
    {
        auto rd3b = [&](int hh, float& u0, float& u1, float& u2) {
            if (hh >= h1s && hh < h1e) {         // staged range == valid rows; else zero pad
                int base = (hh - h1s) * 128 + wcol;
                u0 = (wcol > 0)   ? c1b[base - 1] : 0.f;
                u1 = c1b[base];
                u2 = (wcol < 127) ? c1b[base + 1] : 0.f;
            } else { u0 = u1 = u2 = 0.f; }
        };
        float q0, q1, q2, r0f, r1f, r2f, s0, s1, s2;
        int h2 = h0 + (half << 4);
        rd3b(h2 - 1, q0, q1, q2);
        rd3b(h2, r0f, r1f, r2f);
        float* ob = out + ((size_t)b * 64 + c) * 16384;
        for (int r = 0; r < 16; ++r, ++h2) {
            rd3b(h2 + 1, s0, s1, s2);
            float sum = q0 * wB[0] + q1 * wB[1] + q2 * wB[2]
                      + r0f * wB[3] + r1f * wB[4] + r2f * wB[5]
                      + s0 * wB[6] + s1 * wB[7] + s2 * wB[8];
            ob[h2 * 128 + wcol] = sum;
            q0 = r0f; q1 = r1f; q2 = r2f;
            r0f = s0; r1f = s1; r2f = s2;
        }
    }
}

// ---------------------------------------------------------------------------
extern "C" void kernel_launch(void* const* d_in, const int* in_sizes, int n_in,
                              void* d_out, int out_size, void* d_ws, size_t ws_size,
                              hipStream_t stream)
{
    const float* x   = (const float*)d_in[0];
    const float* lnw = (const float*)d_in[1];
    const float* lnb = (const float*)d_in[2];
    const float* wq  = (const float*)d_in[3];
    const float* wk  = (const float*)d_in[4];
    const float* wv  = (const float*)d_in[5];
    const float* sc  = (const float*)d_in[6];
    const float* wp  = (const float*)d_in[7];
    const float* bp  = (const float*)d_in[8];
    const float* c1w = (const float*)d_in[9];
    const float* c2w = (const float*)d_in[10];
    float* out = (float*)d_out;

    char* ws = (char*)d_ws;
    float*  gpart = (float*)(ws);                 // 8,388,608 B (512 x 4096 f32)
    float2* stats = (float2*)(ws + 8388608);      // 1,048,576 B
    float*  G     = (float*)(ws + 9437184);       //   131,072 B
    float*  w2p   = (float*)(ws + 9568256);       //   524,288 B
    u16*    w2th  = (u16*)(ws + 10092544);        //    73,728 B
    u16*    w2tl  = (u16*)(ws + 10166272);        //    73,728 B  (total 10,240,000 B)

    hipLaunchKernelGGL(k1_ln_gram, dim3(512), dim3(256), 0, stream, x, lnw, lnb, stats, gpart);
    hipLaunchKernelGGL(k1b_reduce, dim3(128), dim3(256), 0, stream, gpart, G);
    hipLaunchKernelGGL(k2_attn, dim3(32), dim3(256), 0, stream, G, wq, wk, wv, sc, wp, w2p);
    hipLaunchKernelGGL(k2b_pack, dim3(8), dim3(512), 0, stream, w2p, w2th, w2tl);
    hipLaunchKernelGGL(k3_proj_conv, dim3(2048), dim3(256), 0, stream,
                       x, stats, lnw, lnb, w2th, w2tl, bp, c1w, c2w, out);
}

// Round 7
// 177.708 us; speedup vs baseline: 1.4875x; 1.1261x over previous
//
#include <hip/hip_runtime.h>
#include <cstdint>
#include <cmath>

typedef uint32_t u32;
typedef unsigned short u16;
typedef float f32x4 __attribute__((ext_vector_type(4)));
typedef short bf16x8 __attribute__((ext_vector_type(8)));

#define NBATCH 8
#define CE 64
#define NPIX 16384

__device__ __forceinline__ u32 bf16_rne(float f) {
    u32 x = __float_as_uint(f);
    return (x + 0x7fffu + ((x >> 16) & 1u)) >> 16;
}

// ---------------------------------------------------------------------------
// K1: per-row LayerNorm over C=64 (stats -> HBM, xn NOT materialized),
// Gram partials G_b = xn^T xn (upper-triangle 8x8 tiles, fp32).
// grid 512 = 8 batches x 64 segs, one 256-row chunk per block, 2 blocks/CU.
// SPILL FIX (r6 profile: 55 MB scratch writes): no register-resident row.
// Stream sum/sumsq during load -> raw x to LDS (static idx) -> per-thread
// in-LDS normalize (static-index b128 round-trip). Rule #20: no runtime-
// indexed register arrays anywhere.
// ---------------------------------------------------------------------------
__global__ __launch_bounds__(256, 2) void k1_ln_gram(
    const float* __restrict__ x, const float* __restrict__ lnw, const float* __restrict__ lnb,
    float2* __restrict__ stats, float* __restrict__ gpart)
{
    __shared__ __align__(16) float sx[256][68];   // 69632 B; +4 pad keeps rows 16B-aligned
    __shared__ float slw[64], slb[64];

    const int t = threadIdx.x;
    const int lane = t & 63;
    const int wv = t >> 6;
    const int blk = blockIdx.x;
    const int b = blk >> 6;
    const int n0 = (blk & 63) << 8;
    const float* xb = x + (size_t)b * (CE * NPIX) + n0 + t;

    if (t < 64) { slw[t] = lnw[t]; slb[t] = lnb[t]; }

    // ---- load (coalesced 1KB segments per channel), stream stats, raw->LDS
    float s = 0.f, s2 = 0.f;
#pragma unroll
    for (int c4 = 0; c4 < 16; ++c4) {
        float v0 = xb[(size_t)(c4 * 4 + 0) * NPIX];
        float v1 = xb[(size_t)(c4 * 4 + 1) * NPIX];
        float v2 = xb[(size_t)(c4 * 4 + 2) * NPIX];
        float v3 = xb[(size_t)(c4 * 4 + 3) * NPIX];
        s  += (v0 + v1) + (v2 + v3);
        s2 += (v0 * v0 + v1 * v1) + (v2 * v2 + v3 * v3);
        float4 v = make_float4(v0, v1, v2, v3);
        *(float4*)&sx[t][c4 * 4] = v;
    }
    const float mu   = s * 0.015625f;
    const float var  = s2 * 0.015625f - mu * mu;   // == E[(x-mu)^2] exactly in reals
    const float rstd = rsqrtf(var + 1e-5f);
    stats[(size_t)b * NPIX + n0 + t] = make_float2(mu, rstd);
    __syncthreads();                 // slw/slb visible (own-row LDS needs no barrier)

    // ---- normalize own row in LDS (static-index b128 round-trip) ----
#pragma unroll
    for (int c4 = 0; c4 < 16; ++c4) {
        float4 v  = *(float4*)&sx[t][c4 * 4];
        float4 w  = *(const float4*)&slw[c4 * 4];   // same addr all lanes: broadcast
        float4 bb = *(const float4*)&slb[c4 * 4];
        v.x = fmaf((v.x - mu) * rstd, w.x, bb.x);
        v.y = fmaf((v.y - mu) * rstd, w.y, bb.y);
        v.z = fmaf((v.z - mu) * rstd, w.z, bb.z);
        v.w = fmaf((v.w - mu) * rstd, w.w, bb.w);
        *(float4*)&sx[t][c4 * 4] = v;
    }
    __syncthreads();

    // ---- Gram over this block's 256 rows (upper-triangle 8x8 tiles) ----
    const int ti = lane >> 3, tj = lane & 7;
    const bool ut = (ti <= tj);          // G symmetric
    const int i0 = ti << 3, j0 = tj << 3;
    float acc[8][8];
#pragma unroll
    for (int p = 0; p < 8; ++p)
#pragma unroll
        for (int q = 0; q < 8; ++q) acc[p][q] = 0.f;

    if (ut) {
#pragma unroll 2
        for (int rr = 0; rr < 64; ++rr) {
            int r = (wv << 6) + rr;
            const float4 a0 = *(const float4*)&sx[r][i0];
            const float4 a1 = *(const float4*)&sx[r][i0 + 4];
            const float4 b0 = *(const float4*)&sx[r][j0];
            const float4 b1 = *(const float4*)&sx[r][j0 + 4];
            float av[8] = {a0.x, a0.y, a0.z, a0.w, a1.x, a1.y, a1.z, a1.w};
            float bv[8] = {b0.x, b0.y, b0.z, b0.w, b1.x, b1.y, b1.z, b1.w};
#pragma unroll
            for (int p = 0; p < 8; ++p)
#pragma unroll
                for (int q = 0; q < 8; ++q) acc[p][q] = fmaf(av[p], bv[q], acc[p][q]);
        }
    }
    __syncthreads();                 // sx reads done -> safe to alias gm over sx

    float (*gm)[66] = (float (*)[66])&sx[0][0];   // 64x66 floats, fits in sx
    for (int w = 0; w < 4; ++w) {
        if (wv == w && ut) {
#pragma unroll
            for (int p = 0; p < 8; ++p)
#pragma unroll
                for (int q = 0; q < 8; ++q) {
                    if (w == 0) gm[i0 + p][j0 + q] = acc[p][q];
                    else        gm[i0 + p][j0 + q] += acc[p][q];
                }
        }
        __syncthreads();
    }
    // write mirrored full 64x64 partial
#pragma unroll
    for (int i = 0; i < 16; ++i) {
        int e = t + (i << 8);
        int r = e >> 6, c2 = e & 63;
        float val = ((r >> 3) <= (c2 >> 3)) ? gm[r][c2] : gm[c2][r];
        gpart[(size_t)blk * 4096 + e] = val;
    }
}

// ---------------------------------------------------------------------------
// K1b: wide reduce of 64 Gram partials per batch. grid 128 = 8 b x 16 segs.
// ---------------------------------------------------------------------------
__global__ __launch_bounds__(256) void k1b_reduce(
    const float* __restrict__ gpart, float* __restrict__ G)
{
    int b = blockIdx.x >> 4;
    int e = ((blockIdx.x & 15) << 8) + threadIdx.x;
    float s0 = 0.f, s1 = 0.f, s2 = 0.f, s3 = 0.f;
#pragma unroll
    for (int p = 0; p < 64; p += 4) {
        s0 += gpart[(size_t)(b * 64 + p) * 4096 + e];
        s1 += gpart[(size_t)(b * 64 + p + 1) * 4096 + e];
        s2 += gpart[(size_t)(b * 64 + p + 2) * 4096 + e];
        s3 += gpart[(size_t)(b * 64 + p + 3) * 4096 + e];
    }
    G[b * 4096 + e] = (s0 + s1) + (s2 + s3);
}

// ---------------------------------------------------------------------------
// K2: per (b,h): attn_pre = wq_h^T G wk_h; *scale; softmax rows (parallel);
// fold into W2part = wv_h @ (attn^T wp_h). All fp32. grid 32.
// ---------------------------------------------------------------------------
__global__ __launch_bounds__(256) void k2_attn(
    const float* __restrict__ G, const float* __restrict__ wq, const float* __restrict__ wk,
    const float* __restrict__ wvm, const float* __restrict__ scale, const float* __restrict__ wp,
    float* __restrict__ w2part)
{
    __shared__ float sg[64][66], swk_[64][66], swq_[64][66], swv_[64][66], swp_[64][66];
    __shared__ float stmp[64][66], satt[64][66];
    const int t = threadIdx.x;
    const int b = blockIdx.x >> 2, h = blockIdx.x & 3;

#pragma unroll
    for (int i = 0; i < 16; ++i) {
        int e = t + (i << 8);
        int r = e >> 6, c = e & 63;
        sg[r][c]   = G[b * 4096 + e];
        swq_[r][c] = wq[r * 256 + h * 64 + c];
        swk_[r][c] = wk[r * 256 + h * 64 + c];
        swv_[r][c] = wvm[r * 256 + h * 64 + c];
        swp_[r][c] = wp[(h * 64 + r) * 64 + c];
    }
    __syncthreads();
    const int rr = t & 63, cb = (t >> 6) << 4;
    float a[16];

    // tmp[cc][e] = sum_k G[cc][k] * wk_h[k][e]
#pragma unroll
    for (int j = 0; j < 16; ++j) a[j] = 0.f;
    for (int k = 0; k < 64; ++k) {
        float g = sg[rr][k];
#pragma unroll
        for (int j = 0; j < 16; ++j) a[j] = fmaf(g, swk_[k][cb + j], a[j]);
    }
#pragma unroll
    for (int j = 0; j < 16; ++j) stmp[rr][cb + j] = a[j];
    __syncthreads();

    // attn_pre[d][e] = sum_cc wq_h[cc][d] * tmp[cc][e], times scale[h]
#pragma unroll
    for (int j = 0; j < 16; ++j) a[j] = 0.f;
    for (int k = 0; k < 64; ++k) {
        float qv = swq_[k][rr];
#pragma unroll
        for (int j = 0; j < 16; ++j) a[j] = fmaf(qv, stmp[k][cb + j], a[j]);
    }
    const float sc = scale[h];
#pragma unroll
    for (int j = 0; j < 16; ++j) satt[rr][cb + j] = a[j] * sc;
    __syncthreads();

    // parallel softmax over e: 4 threads per row, 16 cols each
    {
        const int row = t & 63, q = t >> 6, c0 = q << 4;
        float m = -3.4e38f;
#pragma unroll
        for (int j = 0; j < 16; ++j) m = fmaxf(m, satt[row][c0 + j]);
        stmp[row][q] = m;
        __syncthreads();
        m = fmaxf(fmaxf(stmp[row][0], stmp[row][1]), fmaxf(stmp[row][2], stmp[row][3]));
        float s = 0.f;
#pragma unroll
        for (int j = 0; j < 16; ++j) {
            float p = expf(satt[row][c0 + j] - m);
            satt[row][c0 + j] = p; s += p;
        }
        stmp[row][4 + q] = s;
        __syncthreads();
        float inv = 1.0f / ((stmp[row][4] + stmp[row][5]) + (stmp[row][6] + stmp[row][7]));
#pragma unroll
        for (int j = 0; j < 16; ++j) satt[row][c0 + j] *= inv;
    }
    __syncthreads();

    // weff[e][c] = sum_d attn[d][e] * wp_h[d][c]   -> stmp
#pragma unroll
    for (int j = 0; j < 16; ++j) a[j] = 0.f;
    for (int k = 0; k < 64; ++k) {
        float av = satt[k][rr];
#pragma unroll
        for (int j = 0; j < 16; ++j) a[j] = fmaf(av, swp_[k][cb + j], a[j]);
    }
    __syncthreads();
#pragma unroll
    for (int j = 0; j < 16; ++j) stmp[rr][cb + j] = a[j];
    __syncthreads();

    // w2p[ci][c] = sum_e wv_h[ci][e] * weff[e][c]  -> satt (reused)
#pragma unroll
    for (int j = 0; j < 16; ++j) a[j] = 0.f;
    for (int k = 0; k < 64; ++k) {
        float vv = swv_[rr][k];
#pragma unroll
        for (int j = 0; j < 16; ++j) a[j] = fmaf(vv, stmp[k][cb + j], a[j]);
    }
    __syncthreads();
#pragma unroll
    for (int j = 0; j < 16; ++j) satt[rr][cb + j] = a[j];
    __syncthreads();
#pragma unroll
    for (int i = 0; i < 16; ++i) {
        int e = t + (i << 8);
        w2part[(size_t)blockIdx.x * 4096 + e] = satt[e >> 6][e & 63];
    }
}

// ---------------------------------------------------------------------------
// K2b: W2[b] = sum_h W2part, transpose + split-bf16 pack -> w2t[b][c'][cc(pad72)]
// Output-major: grid 8 x 512 thr, 9 coalesced outputs each (4608 = 9*512).
// ---------------------------------------------------------------------------
__global__ __launch_bounds__(512) void k2b_pack(
    const float* __restrict__ w2part, u16* __restrict__ th, u16* __restrict__ tl)
{
    const int b = blockIdx.x, t = threadIdx.x;
    const float* wp0 = w2part + (size_t)b * 4 * 4096;
#pragma unroll
    for (int i = 0; i < 9; ++i) {
        int o = i * 512 + t;                  // o = cp*72 + cc
        int cp = o / 72, cc = o - cp * 72;
        u32 hb = 0, lb = 0;
        if (cc < 64) {
            int e = cc * 64 + cp;
            float s = ((wp0[e] + wp0[4096 + e]) + (wp0[8192 + e] + wp0[12288 + e]));
            hb = bf16_rne(s);
            lb = bf16_rne(s - __uint_as_float(hb << 16));
        }
        th[b * 4608 + o] = (u16)hb;
        tl[b * 4608 + o] = (u16)lb;
    }
}

// ---------------------------------------------------------------------------
// K3: reconstruct xn rows from x + stats (split-bf16, XOR-swizzled, in-LDS),
// fused proj (3-pass split-bf16 MFMA) + dw-conv1 + exact GELU + dw-conv2.
// grid 2048 = (b, c, strip of 32 h-rows). LDS phase-aliased to 36.9 KB.
// conv pixel (h,w) = proj row n = c*256 + 2h + (w>>6), col c' = w&63.
// ---------------------------------------------------------------------------
__global__ __launch_bounds__(256, 3) void k3_proj_conv(
    const float* __restrict__ x, const float2* __restrict__ stats,
    const float* __restrict__ lnw, const float* __restrict__ lnb,
    const u16* __restrict__ w2th, const u16* __restrict__ w2tl,
    const float* __restrict__ bp, const float* __restrict__ c1w, const float* __restrict__ c2w,
    float* __restrict__ out)
{
    __shared__ __align__(16) char smem[36864];
    u16* sah = (u16*)smem;                  // [72*64] u16, 9216 B
    u16* sal = (u16*)(smem + 9216);         // [72*64]
    u16* swh = (u16*)(smem + 18432);        // [64*72]
    u16* swl = (u16*)(smem + 27648);        // [64*72]
    float* plane = (float*)smem;            // [72*64] f32 — aliases sah/sal
    float* c1b   = (float*)(smem + 18432);  // [34*128] f32 — aliases swh/swl

    const int t = threadIdx.x;
    const int lane = t & 63;
    const int wvi = t >> 6;
    const int bid = blockIdx.x;
    const int s4 = bid & 3;
    const int c = (bid >> 2) & 63;
    const int b = bid >> 8;
    const int h0 = s4 << 5;
    const int rs = max(0, 2 * h0 - 4);
    const int re = min(256, 2 * h0 + 68);
    const int R = re - rs;                       // 68 or 72 proj rows staged

    const float bpv = bp[(wvi << 4) + (lane & 15)];   // early: hide latency

    // ---- stage: x -> xn (affine) -> split-bf16 into sah/sal; W2T -> swh/swl
    {
        const float* xb = x + (size_t)b * (CE * NPIX);
        const float2* st = stats + ((size_t)b * NPIX + c * 256 + rs);
        const int nn0 = c * 256 + rs;
#pragma unroll
        for (int j = 0; j < 8; ++j) {
            int i = (j << 8) + t;                // 0..2047
            int row = i & 127;
            int ccq = i >> 7;                    // 0..15
            if (row < R) {
                int cc0 = ccq << 2;
                float2 ms = st[row];
                float4 lw  = *(const float4*)(lnw + cc0);
                float4 lb4 = *(const float4*)(lnb + cc0);
                size_t gidx = (size_t)cc0 * NPIX + nn0 + row;
                float v0 = xb[gidx];
                float v1 = xb[gidx + NPIX];
                float v2 = xb[gidx + 2 * NPIX];
                float v3 = xb[gidx + 3 * NPIX];
                float x0 = fmaf((v0 - ms.x) * ms.y, lw.x, lb4.x);
                float x1 = fmaf((v1 - ms.x) * ms.y, lw.y, lb4.y);
                float x2 = fmaf((v2 - ms.x) * ms.y, lw.z, lb4.z);
                float x3 = fmaf((v3 - ms.x) * ms.y, lw.w, lb4.w);
                ushort4 hv, lv;
                u32 hb;
                hb = bf16_rne(x0); hv.x = (u16)hb; lv.x = (u16)bf16_rne(x0 - __uint_as_float(hb << 16));
                hb = bf16_rne(x1); hv.y = (u16)hb; lv.y = (u16)bf16_rne(x1 - __uint_as_float(hb << 16));
                hb = bf16_rne(x2); hv.z = (u16)hb; lv.z = (u16)bf16_rne(x2 - __uint_as_float(hb << 16));
                hb = bf16_rne(x3); hv.w = (u16)hb; lv.w = (u16)bf16_rne(x3 - __uint_as_float(hb << 16));
                int cs = cc0 ^ (((rs + row) & 7) << 3);   // XOR-swizzle (elem bits 3-5)
                int base = (row << 6) + cs;
                *(ushort4*)(sah + base) = hv;
                *(ushort4*)(sal + base) = lv;
            }
        }
        const uint4* wsrcH = (const uint4*)(w2th + (size_t)b * 4608);
        const uint4* wsrcL = (const uint4*)(w2tl + (size_t)b * 4608);
        for (int i = t; i < 576; i += 256) {
            ((uint4*)swh)[i] = wsrcH[i];
            ((uint4*)swl)[i] = wsrcL[i];
        }
    }
    __syncthreads();

    // ---- proj GEMM: D[row][col] = sum_cc xn[row][cc] * W2[cc][col] ----
    const int col = (wvi << 4) + (lane & 15);    // wave w owns cols [16w,16w+16)
    const int kg = lane >> 4;
    f32x4 pacc[5];
#pragma unroll
    for (int mt = 0; mt < 5; ++mt) pacc[mt] = (f32x4){0.f, 0.f, 0.f, 0.f};
#pragma unroll
    for (int kk = 0; kk < 2; ++kk) {
        const int k0 = (kk << 5) + (kg << 3);
        bf16x8 bh = *(const bf16x8*)&swh[col * 72 + k0];
        bf16x8 bl = *(const bf16x8*)&swl[col * 72 + k0];
#pragma unroll
        for (int mt = 0; mt < 5; ++mt) {
            int row = (mt << 4) + (lane & 15);
            int sz = (rs + row) & 7;
            int idx = (row << 6) + (k0 ^ (sz << 3));   // undo stage's XOR swizzle
            bf16x8 ah = *(const bf16x8*)&sah[idx];
            bf16x8 al = *(const bf16x8*)&sal[idx];
            pacc[mt] = __builtin_amdgcn_mfma_f32_16x16x32_bf16(ah, bh, pacc[mt], 0, 0, 0);
            pacc[mt] = __builtin_amdgcn_mfma_f32_16x16x32_bf16(ah, bl, pacc[mt], 0, 0, 0);
            pacc[mt] = __builtin_amdgcn_mfma_f32_16x16x32_bf16(al, bh, pacc[mt], 0, 0, 0);
        }
    }
    __syncthreads();     // all LDS reads of sah/sal/swh/swl done -> alias safe

    // ---- write plane (aliases sah/sal) ----
#pragma unroll
    for (int mt = 0; mt < 5; ++mt) {
#pragma unroll
        for (int r = 0; r < 4; ++r) {
            int row = (mt << 4) + (kg << 2) + r;       // D row = (lane>>4)*4 + reg
            if (row < R) plane[(row << 6) + col] = pacc[mt][r] + bpv;
        }
    }
    __syncthreads();

    // ---- conv1 (3x3 depthwise, zero pad) + exact GELU -> c1b (aliases swh/swl)
    float wA[9], wB[9];
#pragma unroll
    for (int q = 0; q < 9; ++q) { wA[q] = c1w[c * 9 + q]; wB[q] = c2w[c * 9 + q]; }
    const int wcol = t & 127;
    const int half = t >> 7;
    const int h1s = max(h0 - 1, 0), h1e = min(h0 + 33, 128);
    const int C1 = h1e - h1s;
    const int pbias = rs << 6;                   // plane idx = h*128 + w - rs*64
    {
        auto rd3 = [&](int hh, float& u0, float& u1, float& u2) {
            if (hh >= 0 && hh < 128) {
                int base = hh * 128 - pbias + wcol;
                u0 = (wcol > 0)   ? plane[base - 1] : 0.f;
                u1 = plane[base];
                u2 = (wcol < 127) ? plane[base + 1] : 0.f;
            } else { u0 = u1 = u2 = 0.f; }
        };
        int rA = (half == 0) ? 0 : ((C1 + 1) >> 1);
        int rB = (half == 0) ? ((C1 + 1) >> 1) : C1;
        float m0, m1, m2, n0_, n1_, n2_, p0, p1, p2;
        int h1 = h1s + rA;
        rd3(h1 - 1, m0, m1, m2);
        rd3(h1, n0_, n1_, n2_);
        for (int r = rA; r < rB; ++r, ++h1) {
            rd3(h1 + 1, p0, p1, p2);
            float sum = m0 * wA[0] + m1 * wA[1] + m2 * wA[2]
                      + n0_ * wA[3] + n1_ * wA[4] + n2_ * wA[5]
                      + p0 * wA[6] + p1 * wA[7] + p2 * wA[8];
            float g = 0.5f * sum * (1.f + erff(sum * 0.70710678118654752f));
            c1b[r * 128 + wcol] = g;
            m0 = n0_; m1 = n1_; m2 = n2_;
            n0_ = p0; n1_ = p1; n2_ = p2;
        }
    }
    __syncthreads();

    // ---- conv2 + global store ----
    {
        auto rd3b = [&](int hh, float& u0, float& u1, float& u2) {
            if (hh >= h1s && hh < h1e) {         // staged range == valid rows; else zero pad
                int base = (hh - h1s) * 128 + wcol;
                u0 = (wcol > 0)   ? c1b[base - 1] : 0.f;
                u1 = c1b[base];
                u2 = (wcol < 127) ? c1b[base + 1] : 0.f;
            } else { u0 = u1 = u2 = 0.f; }
        };
        float q0, q1, q2, r0f, r1f, r2f, s0, s1, s2;
        int h2 = h0 + (half << 4);
        rd3b(h2 - 1, q0, q1, q2);
        rd3b(h2, r0f, r1f, r2f);
        float* ob = out + ((size_t)b * 64 + c) * 16384;
        for (int r = 0; r < 16; ++r, ++h2) {
            rd3b(h2 + 1, s0, s1, s2);
            float sum = q0 * wB[0] + q1 * wB[1] + q2 * wB[2]
                      + r0f * wB[3] + r1f * wB[4] + r2f * wB[5]
                      + s0 * wB[6] + s1 * wB[7] + s2 * wB[8];
            ob[h2 * 128 + wcol] = sum;
            q0 = r0f; q1 = r1f; q2 = r2f;
            r0f = s0; r1f = s1; r2f = s2;
        }
    }
}

// ---------------------------------------------------------------------------
extern "C" void kernel_launch(void* const* d_in, const int* in_sizes, int n_in,
                              void* d_out, int out_size, void* d_ws, size_t ws_size,
                              hipStream_t stream)
{
    const float* x   = (const float*)d_in[0];
    const float* lnw = (const float*)d_in[1];
    const float* lnb = (const float*)d_in[2];
    const float* wq  = (const float*)d_in[3];
    const float* wk  = (const float*)d_in[4];
    const float* wv  = (const float*)d_in[5];
    const float* sc  = (const float*)d_in[6];
    const float* wp  = (const float*)d_in[7];
    const float* bp  = (const float*)d_in[8];
    const float* c1w = (const float*)d_in[9];
    const float* c2w = (const float*)d_in[10];
    float* out = (float*)d_out;

    char* ws = (char*)d_ws;
    float*  gpart = (float*)(ws);                 // 8,388,608 B (512 x 4096 f32)
    float2* stats = (float2*)(ws + 8388608);      // 1,048,576 B
    float*  G     = (float*)(ws + 9437184);       //   131,072 B
    float*  w2p   = (float*)(ws + 9568256);       //   524,288 B
    u16*    w2th  = (u16*)(ws + 10092544);        //    73,728 B
    u16*    w2tl  = (u16*)(ws + 10166272);        //    73,728 B  (total 10,240,000 B)

    hipLaunchKernelGGL(k1_ln_gram, dim3(512), dim3(256), 0, stream, x, lnw, lnb, stats, gpart);
    hipLaunchKernelGGL(k1b_reduce, dim3(128), dim3(256), 0, stream, gpart, G);
    hipLaunchKernelGGL(k2_attn, dim3(32), dim3(256), 0, stream, G, wq, wk, wv, sc, wp, w2p);
    hipLaunchKernelGGL(k2b_pack, dim3(8), dim3(512), 0, stream, w2p, w2th, w2tl);
    hipLaunchKernelGGL(k3_proj_conv, dim3(2048), dim3(256), 0, stream,
                       x, stats, lnw, lnb, w2th, w2tl, bp, c1w, c2w, out);
}